// Round 5
// baseline (319.791 us; speedup 1.0000x reference)
//
#include <hip/hip_runtime.h>
#include <hip/hip_fp16.h>
#include <cstdint>

#define D_IN   256
#define D_OUT  512
#define KK     64
#define BATCH  4096
#define EPSF   1e-12f

// ---------- helpers ----------------------------------------------------------

using half2v = _Float16 __attribute__((ext_vector_type(2)));

__device__ __forceinline__ float dot2(uint32_t a, uint32_t b, float c) {
#if defined(__has_builtin) && __has_builtin(__builtin_amdgcn_fdot2)
  return __builtin_amdgcn_fdot2(__builtin_bit_cast(half2v, a),
                                __builtin_bit_cast(half2v, b), c, false);
#else
  __half2 ah = __builtin_bit_cast(__half2, a);
  __half2 bh = __builtin_bit_cast(__half2, b);
  return c + __half2float(ah.x) * __half2float(bh.x)
           + __half2float(ah.y) * __half2float(bh.y);
#endif
}

__device__ __forceinline__ uint32_t packh2(float a, float b) {
  __half2 h = __floats2half2_rn(a, b);
  return __builtin_bit_cast(uint32_t, h);
}

// ---------- kernel 1: PCHIP slopes -> fp16 pair table -------------------------
// PK2[i][k][o] = {C[o,i,k], d[o,i,k]*(h_k+EPS)}  (4 B)  — uniform knots make
// h per-interval constant to 1 ulp, so one Dh per knot serves both intervals.

__global__ __launch_bounds__(256)
void kan_pack(const float* __restrict__ coeffs,
              const float* __restrict__ knots,
              uint32_t* __restrict__ pk2) {
  __shared__ float s_kn[KK];
  __shared__ float s_h[KK];
  int tid = threadIdx.x;
  if (tid < KK) s_kn[tid] = knots[tid];
  __syncthreads();
  if (tid < KK - 1) s_h[tid] = s_kn[tid + 1] - s_kn[tid];
  __syncthreads();

  int o = blockIdx.x * 256 + tid;   // 0..511
  int i = blockIdx.y;               // 0..255
  const float* C = coeffs + ((size_t)o * D_IN + i) * KK;

  float c[KK];
#pragma unroll
  for (int k = 0; k < KK; k += 4) {
    float4 v = *(const float4*)(C + k);
    c[k] = v.x; c[k + 1] = v.y; c[k + 2] = v.z; c[k + 3] = v.w;
  }

  float d[KK];
  float h0 = s_h[0], h1 = s_h[1];
  float del0 = (c[1] - c[0]) / (h0 + EPSF);
  float del1 = (c[2] - c[1]) / (h1 + EPSF);
  {
    float di = ((2.f * h0 + h1) * del0 - h0 * del1) / (h0 + h1 + EPSF);
    di = (di * del0 <= 0.f) ? 0.f : di;
    di = (fabsf(di) > 3.f * fabsf(del0)) ? 3.f * del0 : di;
    d[0] = di;
  }
  float dp = del0, dn = del1;
#pragma unroll
  for (int k = 1; k <= KK - 2; ++k) {
    float hk = s_h[k], hkm = s_h[k - 1];
    float w1 = 2.f * hk + hkm;
    float w2 = hk + 2.f * hkm;
    float dint = (w1 + w2) / (w1 / (dp + EPSF) + w2 / (dn + EPSF) + EPSF);
    d[k] = (dp * dn > 0.f) ? dint : 0.f;
    if (k < KK - 2) {
      float nd = (c[k + 2] - c[k + 1]) / (s_h[k + 1] + EPSF);
      dp = dn; dn = nd;
    }
  }
  {
    float hN = s_h[KK - 2], hNm = s_h[KK - 3];
    float di = ((2.f * hN + hNm) * dn - hN * dp) / (hN + hNm + EPSF);
    di = (di * dn <= 0.f) ? 0.f : di;
    di = (fabsf(di) > 3.f * fabsf(dn)) ? 3.f * dn : di;
    d[KK - 1] = di;
  }

#pragma unroll
  for (int k = 0; k < KK; ++k) {
    float hk = ((k < KK - 1) ? s_h[k] : s_h[KK - 2]) + EPSF;
    pk2[((size_t)i * KK + k) * D_OUT + o] = packh2(c[k], d[k] * hk);
  }
}

// ---------- kernel 2: per-(b,i) weights + row offsets --------------------------
// W[i*BATCH+b] = {pack(wy0,wd0), pack(wy1,wd1), rbyte=(i*64+k0)*2048, 0}

__global__ __launch_bounds__(512)
void kan_w(const float* __restrict__ x, uint4* __restrict__ W) {
  const int i = blockIdx.x;            // 0..255
  const float inv63 = 1.0f / 63.0f;
  for (int b = threadIdx.x; b < BATCH; b += 512) {
    float xv = x[(size_t)b * D_IN + i];
    float xc = fminf(fmaxf(xv, 0.f), 1.f);
    int k0 = (int)(xc * 63.0f);
    k0 = min(k0, KK - 2);
    float x0 = (float)k0 * inv63;
    if (xc < x0)                              { k0--; x0 -= inv63; }
    else if (k0 < KK - 2 && xc >= x0 + inv63) { k0++; x0 += inv63; }
    float t  = (xc - x0) * 63.0f;
    float t2 = t * t;
    float t3 = t2 * t;
    float wy0 = 2.f * t3 - 3.f * t2 + 1.f;   // h00
    float wy1 = 3.f * t2 - 2.f * t3;         // h01
    float wd0 = t3 - 2.f * t2 + t;           // h10 (h folded into table)
    float wd1 = t3 - t2;                     // h11
    uint4 w;
    w.x = packh2(wy0, wd0);                  // pairs with {C[k0], Dh[k0]}
    w.y = packh2(wy1, wd1);                  // pairs with {C[k0+1], Dh[k0+1]}
    w.z = (uint32_t)(((i << 6) + k0) << 11); // row byte offset (2048 B rows)
    w.w = 0u;
    W[(size_t)i * BATCH + b] = w;            // coalesced across b
  }
}

// ---------- kernel 3: main gather + dot ----------------------------------------
// Block: 512 thr = 8 waves; thread tid <-> o (all 512 o per block -> W read once).
// Block owns 4 batch rows; grid 1024 = 4 blocks/CU = 32 waves/CU.
// i unrolled x2: 16 independent dword gathers in flight per wave.

__global__ __launch_bounds__(512, 8)
void kan_main(const uint4* __restrict__ Wt,
              const char* __restrict__ pkb,
              const float* __restrict__ bias,
              float* __restrict__ out) {
  const int tid = threadIdx.x;
  const int o   = tid;
  const int bw  = blockIdx.x * 4;            // this block's 4 batch rows
  const int vo  = o * 4;                     // lane byte offset within a 2KB row

  float acc[4];
#pragma unroll
  for (int nb = 0; nb < 4; ++nb) acc[nb] = 0.f;

  uint4 wA[4], wB[4];
#pragma unroll
  for (int nb = 0; nb < 4; ++nb) {
    wA[nb] = Wt[bw + nb];                    // i = 0
    wB[nb] = Wt[BATCH + bw + nb];            // i = 1
  }

  for (int i = 0; i < D_IN; i += 2) {
    const int inxt = (i + 2 < D_IN) ? (i + 2) : (D_IN - 2);
    uint4 wC[4], wD[4];
#pragma unroll
    for (int nb = 0; nb < 4; ++nb) {
      wC[nb] = Wt[(size_t)inxt * BATCH + bw + nb];
      wD[nb] = Wt[(size_t)(inxt + 1) * BATCH + bw + nb];
    }

    uint32_t qA0[4], qA1[4], qB0[4], qB1[4];
#pragma unroll
    for (int nb = 0; nb < 4; ++nb) {
      qA0[nb] = *(const uint32_t*)(pkb + wA[nb].z + vo);          // {C[k0],Dh[k0]}
      qA1[nb] = *(const uint32_t*)(pkb + wA[nb].z + 2048 + vo);   // {C[k0+1],Dh[k0+1]}
      qB0[nb] = *(const uint32_t*)(pkb + wB[nb].z + vo);
      qB1[nb] = *(const uint32_t*)(pkb + wB[nb].z + 2048 + vo);
    }

#pragma unroll
    for (int nb = 0; nb < 4; ++nb) {
      acc[nb] = dot2(qA0[nb], wA[nb].x, acc[nb]);
      acc[nb] = dot2(qA1[nb], wA[nb].y, acc[nb]);
      acc[nb] = dot2(qB0[nb], wB[nb].x, acc[nb]);
      acc[nb] = dot2(qB1[nb], wB[nb].y, acc[nb]);
    }

#pragma unroll
    for (int nb = 0; nb < 4; ++nb) { wA[nb] = wC[nb]; wB[nb] = wD[nb]; }
  }

  float bv = bias[o];
#pragma unroll
  for (int nb = 0; nb < 4; ++nb)
    out[(size_t)(bw + nb) * D_OUT + o] = acc[nb] + bv;
}

// ---------- launch -------------------------------------------------------------

extern "C" void kernel_launch(void* const* d_in, const int* in_sizes, int n_in,
                              void* d_out, int out_size, void* d_ws, size_t ws_size,
                              hipStream_t stream) {
  const float* x      = (const float*)d_in[0];
  const float* coeffs = (const float*)d_in[1];
  const float* bias   = (const float*)d_in[2];
  const float* knots  = (const float*)d_in[3];
  float* out = (float*)d_out;

  const size_t pk_bytes = (size_t)D_IN * KK * D_OUT * 4;   // 32 MiB
  const size_t w_bytes  = (size_t)D_IN * BATCH * 16;       // 16 MiB
  if (ws_size < pk_bytes + w_bytes) return;  // loud failure (out stays poisoned)

  char* ws = (char*)d_ws;
  uint32_t* pk2 = (uint32_t*)ws;
  uint4*    W   = (uint4*)(ws + pk_bytes);

  kan_pack<<<dim3(D_OUT / 256, D_IN), 256, 0, stream>>>(coeffs, knots, pk2);
  kan_w   <<<D_IN, 512, 0, stream>>>(x, W);
  kan_main<<<dim3(BATCH / 4), 512, 0, stream>>>(W, (const char*)pk2, bias, out);
}

// Round 6
// 312.719 us; speedup vs baseline: 1.0226x; 1.0226x over previous
//
#include <hip/hip_runtime.h>
#include <hip/hip_fp16.h>
#include <cstdint>

#define D_IN   256
#define D_OUT  512
#define KK     64
#define BATCH  4096
#define EPSF   1e-12f

// ---------- helpers ----------------------------------------------------------

using half2v = _Float16 __attribute__((ext_vector_type(2)));

__device__ __forceinline__ float dot2(uint32_t a, uint32_t b, float c) {
#if defined(__has_builtin) && __has_builtin(__builtin_amdgcn_fdot2)
  return __builtin_amdgcn_fdot2(__builtin_bit_cast(half2v, a),
                                __builtin_bit_cast(half2v, b), c, false);
#else
  __half2 ah = __builtin_bit_cast(__half2, a);
  __half2 bh = __builtin_bit_cast(__half2, b);
  return c + __half2float(ah.x) * __half2float(bh.x)
           + __half2float(ah.y) * __half2float(bh.y);
#endif
}

__device__ __forceinline__ uint32_t packh2(float a, float b) {
  __half2 h = __floats2half2_rn(a, b);
  return __builtin_bit_cast(uint32_t, h);
}

// ---------- kernel 1: PCHIP slopes -> fp16 pair table -------------------------
// PK2[i][k][o] = {C[o,i,k], d[o,i,k]*(h_k+EPS)}  (4 B). Row = 2048 B.

__global__ __launch_bounds__(256)
void kan_pack(const float* __restrict__ coeffs,
              const float* __restrict__ knots,
              uint32_t* __restrict__ pk2) {
  __shared__ float s_kn[KK];
  __shared__ float s_h[KK];
  int tid = threadIdx.x;
  if (tid < KK) s_kn[tid] = knots[tid];
  __syncthreads();
  if (tid < KK - 1) s_h[tid] = s_kn[tid + 1] - s_kn[tid];
  __syncthreads();

  int o = blockIdx.x * 256 + tid;   // 0..511
  int i = blockIdx.y;               // 0..255
  const float* C = coeffs + ((size_t)o * D_IN + i) * KK;

  float c[KK];
#pragma unroll
  for (int k = 0; k < KK; k += 4) {
    float4 v = *(const float4*)(C + k);
    c[k] = v.x; c[k + 1] = v.y; c[k + 2] = v.z; c[k + 3] = v.w;
  }

  float d[KK];
  float h0 = s_h[0], h1 = s_h[1];
  float del0 = (c[1] - c[0]) / (h0 + EPSF);
  float del1 = (c[2] - c[1]) / (h1 + EPSF);
  {
    float di = ((2.f * h0 + h1) * del0 - h0 * del1) / (h0 + h1 + EPSF);
    di = (di * del0 <= 0.f) ? 0.f : di;
    di = (fabsf(di) > 3.f * fabsf(del0)) ? 3.f * del0 : di;
    d[0] = di;
  }
  float dp = del0, dn = del1;
#pragma unroll
  for (int k = 1; k <= KK - 2; ++k) {
    float hk = s_h[k], hkm = s_h[k - 1];
    float w1 = 2.f * hk + hkm;
    float w2 = hk + 2.f * hkm;
    float dint = (w1 + w2) / (w1 / (dp + EPSF) + w2 / (dn + EPSF) + EPSF);
    d[k] = (dp * dn > 0.f) ? dint : 0.f;
    if (k < KK - 2) {
      float nd = (c[k + 2] - c[k + 1]) / (s_h[k + 1] + EPSF);
      dp = dn; dn = nd;
    }
  }
  {
    float hN = s_h[KK - 2], hNm = s_h[KK - 3];
    float di = ((2.f * hN + hNm) * dn - hN * dp) / (hN + hNm + EPSF);
    di = (di * dn <= 0.f) ? 0.f : di;
    di = (fabsf(di) > 3.f * fabsf(dn)) ? 3.f * dn : di;
    d[KK - 1] = di;
  }

#pragma unroll
  for (int k = 0; k < KK; ++k) {
    float hk = ((k < KK - 1) ? s_h[k] : s_h[KK - 2]) + EPSF;
    pk2[((size_t)i * KK + k) * D_OUT + o] = packh2(c[k], d[k] * hk);
  }
}

// ---------- kernel 2: per-(b,i) weights (8B) + interval index (1B) -------------
// W8[i*BATCH+b] = {pack(wy0,wd0), pack(wy1,wd1)};  K0[i*BATCH+b] = k0

__global__ __launch_bounds__(512)
void kan_w(const float* __restrict__ x, uint2* __restrict__ W8,
           unsigned char* __restrict__ K0) {
  const int i = blockIdx.x;            // 0..255
  const float inv63 = 1.0f / 63.0f;
  for (int b = threadIdx.x; b < BATCH; b += 512) {
    float xv = x[(size_t)b * D_IN + i];
    float xc = fminf(fmaxf(xv, 0.f), 1.f);
    int k0 = (int)(xc * 63.0f);
    k0 = min(k0, KK - 2);
    float x0 = (float)k0 * inv63;
    if (xc < x0)                              { k0--; x0 -= inv63; }
    else if (k0 < KK - 2 && xc >= x0 + inv63) { k0++; x0 += inv63; }
    float t  = (xc - x0) * 63.0f;
    float t2 = t * t;
    float t3 = t2 * t;
    float wy0 = 2.f * t3 - 3.f * t2 + 1.f;   // h00
    float wy1 = 3.f * t2 - 2.f * t3;         // h01
    float wd0 = t3 - 2.f * t2 + t;           // h10 (h folded into table)
    float wd1 = t3 - t2;                     // h11
    uint2 w;
    w.x = packh2(wy0, wd0);                  // pairs with {C[k0],   Dh[k0]}
    w.y = packh2(wy1, wd1);                  // pairs with {C[k0+1], Dh[k0+1]}
    W8[(size_t)i * BATCH + b] = w;
    K0[(size_t)i * BATCH + b] = (unsigned char)k0;
  }
}

// ---------- kernel 3: main gather + dot, i-chunked & XCD-pinned ----------------
// Job = (chunk of CI i's, o-half, b-tile of 16). bid&7 selects the XCD lane;
// chunk = lane % nchunk  ->  each XCD re-reads ONLY its 2 MiB PK slice (L2-fits).
// Block: 512 thr; og = tid&255 (o within half), bg = tid>>8 -> 8 batch rows.
// Writes f32 partials P[chunk][b][o] (no bias).

__global__ __launch_bounds__(512, 8)
void kan_main(const uint2* __restrict__ W8, const unsigned char* __restrict__ K0,
              const char* __restrict__ pkb, float* __restrict__ P,
              int lg /* log2(nchunk) */) {
  const int bid   = blockIdx.x;
  const int lane8 = bid & 7;               // XCD lane (round-robin dispatch)
  const int j     = bid >> 3;
  const int nchm1 = (1 << lg) - 1;
  const int chunk = lane8 & nchm1;
  const int sub   = lane8 >> lg;           // extra lanes split the b-tile space
  const int G     = 8 >> lg;
  const int w     = j * G + sub;           // 0..511
  const int oh    = w >> 8;                // o-half
  const int btile = w & 255;
  const int CI    = D_IN >> lg;
  const int i0    = chunk * CI;

  const int tid = threadIdx.x;
  const int og  = tid & 255;
  const int bg  = tid >> 8;
  const int b_base = btile * 16 + bg * 8;
  const uint32_t obyte = (uint32_t)(oh * 1024 + og * 4);

  float acc[8];
#pragma unroll
  for (int nb = 0; nb < 8; ++nb) acc[nb] = 0.f;

  for (int ic = 0; ic < CI; ++ic) {
    const int i = i0 + ic;
    const size_t wbase = (size_t)i * BATCH + b_base;
    const uint4* wp = (const uint4*)(W8 + wbase);   // 8 consecutive uint2
    uint4 wv0 = wp[0], wv1 = wp[1], wv2 = wp[2], wv3 = wp[3];
    uint64_t k8 = *(const uint64_t*)(K0 + wbase);   // 8 interval bytes

    uint32_t q0[8], q1[8];
#pragma unroll
    for (int nb = 0; nb < 8; ++nb) {
      uint32_t k0 = (uint32_t)((k8 >> (8 * nb)) & 0xFF);
      uint32_t rb = (((uint32_t)i << 6) + k0) << 11;   // row * 2048 B
      const char* a = pkb + rb + obyte;
      q0[nb] = *(const uint32_t*)a;                    // {C[k0],  Dh[k0]}
      q1[nb] = *(const uint32_t*)(a + 2048);           // {C[k0+1],Dh[k0+1]}
    }

    acc[0] = dot2(q0[0], wv0.x, acc[0]); acc[0] = dot2(q1[0], wv0.y, acc[0]);
    acc[1] = dot2(q0[1], wv0.z, acc[1]); acc[1] = dot2(q1[1], wv0.w, acc[1]);
    acc[2] = dot2(q0[2], wv1.x, acc[2]); acc[2] = dot2(q1[2], wv1.y, acc[2]);
    acc[3] = dot2(q0[3], wv1.z, acc[3]); acc[3] = dot2(q1[3], wv1.w, acc[3]);
    acc[4] = dot2(q0[4], wv2.x, acc[4]); acc[4] = dot2(q1[4], wv2.y, acc[4]);
    acc[5] = dot2(q0[5], wv2.z, acc[5]); acc[5] = dot2(q1[5], wv2.w, acc[5]);
    acc[6] = dot2(q0[6], wv3.x, acc[6]); acc[6] = dot2(q1[6], wv3.y, acc[6]);
    acc[7] = dot2(q0[7], wv3.z, acc[7]); acc[7] = dot2(q1[7], wv3.w, acc[7]);
  }

  float* Pc = P + ((size_t)chunk * BATCH + b_base) * D_OUT + oh * 256 + og;
#pragma unroll
  for (int nb = 0; nb < 8; ++nb)
    Pc[(size_t)nb * D_OUT] = acc[nb];
}

// ---------- kernel 4: reduce partials + bias -----------------------------------

__global__ __launch_bounds__(512)
void kan_reduce(const float* __restrict__ P, const float* __restrict__ bias,
                float* __restrict__ out, int nchunk) {
  const size_t t = (size_t)blockIdx.x * 512 + threadIdx.x;  // float4 index
  const int o4 = (int)(t & 127);                            // (D_OUT/4)-1
  float4 s = ((const float4*)bias)[o4];
  const size_t stride = (size_t)BATCH * D_OUT / 4;
  for (int c = 0; c < nchunk; ++c) {
    float4 v = ((const float4*)P)[c * stride + t];
    s.x += v.x; s.y += v.y; s.z += v.z; s.w += v.w;
  }
  ((float4*)out)[t] = s;
}

// ---------- launch -------------------------------------------------------------

extern "C" void kernel_launch(void* const* d_in, const int* in_sizes, int n_in,
                              void* d_out, int out_size, void* d_ws, size_t ws_size,
                              hipStream_t stream) {
  const float* x      = (const float*)d_in[0];
  const float* coeffs = (const float*)d_in[1];
  const float* bias   = (const float*)d_in[2];
  const float* knots  = (const float*)d_in[3];
  float* out = (float*)d_out;

  const size_t pk_bytes = (size_t)D_IN * KK * D_OUT * 4;   // 32 MiB
  const size_t w_bytes  = (size_t)D_IN * BATCH * 8;        //  8 MiB
  const size_t k_bytes  = (size_t)D_IN * BATCH;            //  1 MiB
  const size_t fixed    = pk_bytes + w_bytes + k_bytes;
  const size_t p_one    = (size_t)BATCH * D_OUT * 4;       //  8 MiB per partial

  int lg = 3;                                              // prefer 8 chunks
  while (lg > 0 && ws_size < fixed + (p_one << lg)) lg--;
  if (ws_size < fixed + (p_one << lg)) return;             // loud failure
  const int nchunk = 1 << lg;

  char* ws = (char*)d_ws;
  uint32_t*      pk2 = (uint32_t*)ws;
  uint2*         W8  = (uint2*)(ws + pk_bytes);
  unsigned char* K0  = (unsigned char*)(ws + pk_bytes + w_bytes);
  float*         P   = (float*)(ws + fixed);

  kan_pack<<<dim3(D_OUT / 256, D_IN), 256, 0, stream>>>(coeffs, knots, pk2);
  kan_w   <<<D_IN, 512, 0, stream>>>(x, W8, K0);
  kan_main<<<dim3(512 * nchunk), 512, 0, stream>>>(W8, K0, (const char*)pk2, P, lg);
  kan_reduce<<<dim3(BATCH * D_OUT / 4 / 512), 512, 0, stream>>>(P, bias, out, nchunk);
}

// Round 7
// 138.590 us; speedup vs baseline: 2.3075x; 2.2564x over previous
//
#include <hip/hip_runtime.h>
#include <hip/hip_fp16.h>
#include <cstdint>

#define D_IN   256
#define D_OUT  512
#define KK     64
#define BATCH  4096
#define EPSF   1e-12f

#define NCH    4                 // i-chunks (partials)
#define CI     (D_IN / NCH)      // 64 i per block
#define BT     128               // b-tile per block

// ---------- helpers ----------------------------------------------------------

using half2v = _Float16 __attribute__((ext_vector_type(2)));

__device__ __forceinline__ float dot2(uint32_t a, uint32_t b, float c) {
#if defined(__has_builtin) && __has_builtin(__builtin_amdgcn_fdot2)
  return __builtin_amdgcn_fdot2(__builtin_bit_cast(half2v, a),
                                __builtin_bit_cast(half2v, b), c, false);
#else
  __half2 ah = __builtin_bit_cast(__half2, a);
  __half2 bh = __builtin_bit_cast(__half2, b);
  return c + __half2float(ah.x) * __half2float(bh.x)
           + __half2float(ah.y) * __half2float(bh.y);
#endif
}

__device__ __forceinline__ uint32_t packh2(float a, float b) {
  __half2 h = __floats2half2_rn(a, b);
  return __builtin_bit_cast(uint32_t, h);
}

// ---------- kernel 1: PCHIP slopes -> fp16 pair table (staging-permuted) -------
// pk2p[((i*4 + oq)*64 + k)*128 + og] = {C[o,i,k], d[o,i,k]*(h_k+EPS)} (4 B)
// where o = oq*128 + og.  Slab (i,oq) = 32 KB contiguous -> linear LDS staging.

__global__ __launch_bounds__(256)
void kan_pack(const float* __restrict__ coeffs,
              const float* __restrict__ knots,
              uint32_t* __restrict__ pk2p) {
  __shared__ float s_kn[KK];
  __shared__ float s_h[KK];
  int tid = threadIdx.x;
  if (tid < KK) s_kn[tid] = knots[tid];
  __syncthreads();
  if (tid < KK - 1) s_h[tid] = s_kn[tid + 1] - s_kn[tid];
  __syncthreads();

  int o = blockIdx.x * 256 + tid;   // 0..511
  int i = blockIdx.y;               // 0..255
  const float* C = coeffs + ((size_t)o * D_IN + i) * KK;

  float c[KK];
#pragma unroll
  for (int k = 0; k < KK; k += 4) {
    float4 v = *(const float4*)(C + k);
    c[k] = v.x; c[k + 1] = v.y; c[k + 2] = v.z; c[k + 3] = v.w;
  }

  float d[KK];
  float h0 = s_h[0], h1 = s_h[1];
  float del0 = (c[1] - c[0]) / (h0 + EPSF);
  float del1 = (c[2] - c[1]) / (h1 + EPSF);
  {
    float di = ((2.f * h0 + h1) * del0 - h0 * del1) / (h0 + h1 + EPSF);
    di = (di * del0 <= 0.f) ? 0.f : di;
    di = (fabsf(di) > 3.f * fabsf(del0)) ? 3.f * del0 : di;
    d[0] = di;
  }
  float dp = del0, dn = del1;
#pragma unroll
  for (int k = 1; k <= KK - 2; ++k) {
    float hk = s_h[k], hkm = s_h[k - 1];
    float w1 = 2.f * hk + hkm;
    float w2 = hk + 2.f * hkm;
    float dint = (w1 + w2) / (w1 / (dp + EPSF) + w2 / (dn + EPSF) + EPSF);
    d[k] = (dp * dn > 0.f) ? dint : 0.f;
    if (k < KK - 2) {
      float nd = (c[k + 2] - c[k + 1]) / (s_h[k + 1] + EPSF);
      dp = dn; dn = nd;
    }
  }
  {
    float hN = s_h[KK - 2], hNm = s_h[KK - 3];
    float di = ((2.f * hN + hNm) * dn - hN * dp) / (hN + hNm + EPSF);
    di = (di * dn <= 0.f) ? 0.f : di;
    di = (fabsf(di) > 3.f * fabsf(dn)) ? 3.f * dn : di;
    d[KK - 1] = di;
  }

  const int oq = o >> 7, og = o & 127;
#pragma unroll
  for (int k = 0; k < KK; ++k) {
    float hk = ((k < KK - 1) ? s_h[k] : s_h[KK - 2]) + EPSF;
    pk2p[((size_t)(((i << 2) + oq) << 6) + k) * 128 + og] = packh2(c[k], d[k] * hk);
  }
}

// ---------- kernel 2: per-(b,i) weights (8B) + interval index (1B) -------------
// W8[i*BATCH+b] = {pack(wy0,wd0), pack(wy1,wd1)};  K0[i*BATCH+b] = k0

__global__ __launch_bounds__(512)
void kan_w(const float* __restrict__ x, uint2* __restrict__ W8,
           unsigned char* __restrict__ K0) {
  const int i = blockIdx.x;            // 0..255
  const float inv63 = 1.0f / 63.0f;
  for (int b = threadIdx.x; b < BATCH; b += 512) {
    float xv = x[(size_t)b * D_IN + i];
    float xc = fminf(fmaxf(xv, 0.f), 1.f);
    int k0 = (int)(xc * 63.0f);
    k0 = min(k0, KK - 2);
    float x0 = (float)k0 * inv63;
    if (xc < x0)                              { k0--; x0 -= inv63; }
    else if (k0 < KK - 2 && xc >= x0 + inv63) { k0++; x0 += inv63; }
    float t  = (xc - x0) * 63.0f;
    float t2 = t * t;
    float t3 = t2 * t;
    float wy0 = 2.f * t3 - 3.f * t2 + 1.f;   // h00
    float wy1 = 3.f * t2 - 2.f * t3;         // h01
    float wd0 = t3 - 2.f * t2 + t;           // h10 (h folded into table)
    float wd1 = t3 - t2;                     // h11
    uint2 w;
    w.x = packh2(wy0, wd0);                  // pairs with {C[k0],   Dh[k0]}
    w.y = packh2(wy1, wd1);                  // pairs with {C[k0+1], Dh[k0+1]}
    W8[(size_t)i * BATCH + b] = w;
    K0[(size_t)i * BATCH + b] = (unsigned char)k0;
  }
}

// ---------- kernel 3: LDS-staged main -----------------------------------------
// Block: 512 thr. Covers (o-quarter 128 o) x (BT=128 b) x (CI=64 i).
// Per i: 32 KB slab in LDS (double-buffered), reg-staged (T14: issue i+1 loads
// early, ds_write after consume, 1 barrier/iter). Consume: thread (g=tid&31,
// s=tid>>5) owns og 4g..4g+3 and 8 b's: 2x ds_read_b128 (rows k0,k0+1) + 8 dot2.
// Writes fp16 partials P[chunk][b][o].

__global__ __launch_bounds__(512, 4)
void kan_main(const uint2* __restrict__ W8, const unsigned char* __restrict__ K0,
              const uint4* __restrict__ pkq, __half* __restrict__ P) {
  __shared__ uint4 sb[2][2048];              // 2 x 32 KB

  const int bid   = blockIdx.x;
  const int chunk = bid & 3;                 // low bits -> spread across XCDs
  const int rest  = bid >> 2;
  const int oq    = rest & 3;
  const int btile = rest >> 2;               // 0..31
  const int tid   = threadIdx.x;
  const int g     = tid & 31;                // og-group of 4
  const int s     = tid >> 5;                // 0..15 -> 8 b's each
  const int bbase = btile * BT + s * 8;
  const int i0    = chunk * CI;

  float acc[8][4];
#pragma unroll
  for (int j = 0; j < 8; ++j)
#pragma unroll
    for (int m = 0; m < 4; ++m) acc[j][m] = 0.f;

  // ---- prologue: W(i0), K0(i0), stage slab(i0) into buf 0 ----
  uint4 wreg[4];
  uint64_t k8;
  {
    const uint4* wp = (const uint4*)(W8 + (size_t)i0 * BATCH + bbase);
#pragma unroll
    for (int n = 0; n < 4; ++n) wreg[n] = wp[n];
    k8 = *(const uint64_t*)(K0 + (size_t)i0 * BATCH + bbase);
  }
  {
    const uint4* src = pkq + ((size_t)((i0 << 2) + oq) << 11);
    uint4 r0 = src[tid], r1 = src[tid + 512], r2 = src[tid + 1024], r3 = src[tid + 1536];
    sb[0][tid] = r0; sb[0][tid + 512] = r1; sb[0][tid + 1024] = r2; sb[0][tid + 1536] = r3;
  }
  __syncthreads();

  for (int ic = 0; ic < CI; ++ic) {
    const int cur = ic & 1;
    const int i   = i0 + ic;
    const bool more = (ic + 1 < CI);

    // ---- issue next-i loads early (overlap with consume) ----
    uint4 r0, r1, r2, r3, wnxt[4];
    uint64_t k8n = 0;
    if (more) {
      const uint4* src = pkq + ((size_t)(((i + 1) << 2) + oq) << 11);
      r0 = src[tid]; r1 = src[tid + 512]; r2 = src[tid + 1024]; r3 = src[tid + 1536];
      const uint4* wp = (const uint4*)(W8 + (size_t)(i + 1) * BATCH + bbase);
#pragma unroll
      for (int n = 0; n < 4; ++n) wnxt[n] = wp[n];
      k8n = *(const uint64_t*)(K0 + (size_t)(i + 1) * BATCH + bbase);
    }

    // ---- consume current slab from LDS ----
    const uint4* bufc = sb[cur];
#pragma unroll
    for (int j = 0; j < 8; ++j) {
      const uint32_t k0 = (uint32_t)(k8 >> (8 * j)) & 0xFFu;
      const uint4* p = bufc + k0 * 32 + g;
      uint4 q0 = p[0];                        // {C,Dh} for og 4g..4g+3, row k0
      uint4 q1 = p[32];                       // row k0+1
      uint4 t  = wreg[j >> 1];
      uint32_t w0 = (j & 1) ? t.z : t.x;      // {wy0,wd0}
      uint32_t w1 = (j & 1) ? t.w : t.y;      // {wy1,wd1}
      acc[j][0] = dot2(q0.x, w0, acc[j][0]); acc[j][0] = dot2(q1.x, w1, acc[j][0]);
      acc[j][1] = dot2(q0.y, w0, acc[j][1]); acc[j][1] = dot2(q1.y, w1, acc[j][1]);
      acc[j][2] = dot2(q0.z, w0, acc[j][2]); acc[j][2] = dot2(q1.z, w1, acc[j][2]);
      acc[j][3] = dot2(q0.w, w0, acc[j][3]); acc[j][3] = dot2(q1.w, w1, acc[j][3]);
    }

    // ---- write next slab into other buffer, rotate W regs ----
    if (more) {
      uint4* bufn = sb[cur ^ 1];
      bufn[tid] = r0; bufn[tid + 512] = r1; bufn[tid + 1024] = r2; bufn[tid + 1536] = r3;
#pragma unroll
      for (int n = 0; n < 4; ++n) wreg[n] = wnxt[n];
      k8 = k8n;
    }
    __syncthreads();
  }

  // ---- fp16 partials ----
  const size_t pb = ((size_t)chunk * BATCH + bbase) * D_OUT + oq * 128 + g * 4;
#pragma unroll
  for (int j = 0; j < 8; ++j) {
    uint2 h;
    h.x = packh2(acc[j][0], acc[j][1]);
    h.y = packh2(acc[j][2], acc[j][3]);
    *(uint2*)((char*)P + (pb + (size_t)j * D_OUT) * 2) = h;
  }
}

// ---------- kernel 4: reduce fp16 partials + bias ------------------------------

__global__ __launch_bounds__(256)
void kan_reduce(const __half* __restrict__ P, const float* __restrict__ bias,
                float* __restrict__ out) {
  const size_t t = (size_t)blockIdx.x * 256 + threadIdx.x;  // 4-o unit
  const int o4 = (int)(t & 127);
  float4 sum = ((const float4*)bias)[o4];
#pragma unroll
  for (int c = 0; c < NCH; ++c) {
    uint2 h = *(const uint2*)((const char*)P +
              ((size_t)c * BATCH * D_OUT + t * 4) * 2);
    __half2 h01 = __builtin_bit_cast(__half2, h.x);
    __half2 h23 = __builtin_bit_cast(__half2, h.y);
    sum.x += __half2float(h01.x); sum.y += __half2float(h01.y);
    sum.z += __half2float(h23.x); sum.w += __half2float(h23.y);
  }
  ((float4*)out)[t] = sum;
}

// ---------- launch -------------------------------------------------------------

extern "C" void kernel_launch(void* const* d_in, const int* in_sizes, int n_in,
                              void* d_out, int out_size, void* d_ws, size_t ws_size,
                              hipStream_t stream) {
  const float* x      = (const float*)d_in[0];
  const float* coeffs = (const float*)d_in[1];
  const float* bias   = (const float*)d_in[2];
  const float* knots  = (const float*)d_in[3];
  float* out = (float*)d_out;

  const size_t pk_bytes = (size_t)D_IN * KK * D_OUT * 4;     // 32 MiB
  const size_t w_bytes  = (size_t)D_IN * BATCH * 8;          //  8 MiB
  const size_t k_bytes  = (size_t)D_IN * BATCH;              //  1 MiB
  const size_t p_bytes  = (size_t)NCH * BATCH * D_OUT * 2;   // 16 MiB fp16 partials
  if (ws_size < pk_bytes + w_bytes + k_bytes + p_bytes) return;  // loud failure

  char* ws = (char*)d_ws;
  uint32_t*      pk2p = (uint32_t*)ws;
  uint2*         W8   = (uint2*)(ws + pk_bytes);
  unsigned char* K0   = (unsigned char*)(ws + pk_bytes + w_bytes);
  __half*        P    = (__half*)(ws + pk_bytes + w_bytes + k_bytes);

  kan_pack<<<dim3(D_OUT / 256, D_IN), 256, 0, stream>>>(coeffs, knots, pk2p);
  kan_w   <<<D_IN, 512, 0, stream>>>(x, W8, K0);
  kan_main<<<dim3(NCH * 4 * (BATCH / BT)), 512, 0, stream>>>(W8, K0,
            (const uint4*)pk2p, P);
  kan_reduce<<<dim3(BATCH * D_OUT / 4 / 256), 256, 0, stream>>>(P, bias, out);
}

// Round 8
// 126.634 us; speedup vs baseline: 2.5253x; 1.0944x over previous
//
#include <hip/hip_runtime.h>
#include <hip/hip_fp16.h>
#include <cstdint>

#define D_IN   256
#define D_OUT  512
#define KK     64
#define BATCH  4096
#define EPSF   1e-12f
#define BT     256               // batch rows per block (1024 threads)

// ---------- helpers ----------------------------------------------------------

using half2v = _Float16 __attribute__((ext_vector_type(2)));

__device__ __forceinline__ float dot2(uint32_t a, uint32_t b, float c) {
#if defined(__has_builtin) && __has_builtin(__builtin_amdgcn_fdot2)
  return __builtin_amdgcn_fdot2(__builtin_bit_cast(half2v, a),
                                __builtin_bit_cast(half2v, b), c, false);
#else
  __half2 ah = __builtin_bit_cast(__half2, a);
  __half2 bh = __builtin_bit_cast(__half2, b);
  return c + __half2float(ah.x) * __half2float(bh.x)
           + __half2float(ah.y) * __half2float(bh.y);
#endif
}

__device__ __forceinline__ uint32_t packh2(float a, float b) {
  __half2 h = __floats2half2_rn(a, b);
  return __builtin_bit_cast(uint32_t, h);
}

// ---------- kernel 1: fused prep ------------------------------------------------
// Blocks [0,512): PCHIP slopes -> fp16 pair table, staging-permuted:
//   pk2p[((i*4+oq)*64 + k)*128 + og] = {C[o,i,k], d[o,i,k]*(h_k+EPS)}, o=oq*128+og
// Blocks [512,768): per-(b,i) Hermite weights (8B) + interval index (1B):
//   W8[i*BATCH+b] = {pack(wy0,wd0), pack(wy1,wd1)};  K0[i*BATCH+b] = k0

__global__ __launch_bounds__(256)
void kan_prep(const float* __restrict__ coeffs, const float* __restrict__ knots,
              const float* __restrict__ x,
              uint32_t* __restrict__ pk2p, uint2* __restrict__ W8,
              unsigned char* __restrict__ K0) {
  __shared__ float s_kn[KK];
  __shared__ float s_h[KK];
  const int bid = blockIdx.x;
  const int tid = threadIdx.x;

  if (bid < 512) {
    // ---------------- pack body ----------------
    if (tid < KK) s_kn[tid] = knots[tid];
    __syncthreads();
    if (tid < KK - 1) s_h[tid] = s_kn[tid + 1] - s_kn[tid];
    __syncthreads();

    const int i = bid >> 1;
    const int o = (bid & 1) * 256 + tid;
    const float* C = coeffs + ((size_t)o * D_IN + i) * KK;

    float c[KK];
#pragma unroll
    for (int k = 0; k < KK; k += 4) {
      float4 v = *(const float4*)(C + k);
      c[k] = v.x; c[k + 1] = v.y; c[k + 2] = v.z; c[k + 3] = v.w;
    }

    float d[KK];
    float h0 = s_h[0], h1 = s_h[1];
    float del0 = (c[1] - c[0]) / (h0 + EPSF);
    float del1 = (c[2] - c[1]) / (h1 + EPSF);
    {
      float di = ((2.f * h0 + h1) * del0 - h0 * del1) / (h0 + h1 + EPSF);
      di = (di * del0 <= 0.f) ? 0.f : di;
      di = (fabsf(di) > 3.f * fabsf(del0)) ? 3.f * del0 : di;
      d[0] = di;
    }
    float dp = del0, dn = del1;
#pragma unroll
    for (int k = 1; k <= KK - 2; ++k) {
      float hk = s_h[k], hkm = s_h[k - 1];
      float w1 = 2.f * hk + hkm;
      float w2 = hk + 2.f * hkm;
      float dint = (w1 + w2) / (w1 / (dp + EPSF) + w2 / (dn + EPSF) + EPSF);
      d[k] = (dp * dn > 0.f) ? dint : 0.f;
      if (k < KK - 2) {
        float nd = (c[k + 2] - c[k + 1]) / (s_h[k + 1] + EPSF);
        dp = dn; dn = nd;
      }
    }
    {
      float hN = s_h[KK - 2], hNm = s_h[KK - 3];
      float di = ((2.f * hN + hNm) * dn - hN * dp) / (hN + hNm + EPSF);
      di = (di * dn <= 0.f) ? 0.f : di;
      di = (fabsf(di) > 3.f * fabsf(dn)) ? 3.f * dn : di;
      d[KK - 1] = di;
    }

    const int oq = o >> 7, og = o & 127;
#pragma unroll
    for (int k = 0; k < KK; ++k) {
      float hk = ((k < KK - 1) ? s_h[k] : s_h[KK - 2]) + EPSF;
      pk2p[((size_t)(((i << 2) + oq) << 6) + k) * 128 + og] = packh2(c[k], d[k] * hk);
    }
  } else {
    // ---------------- weights body ----------------
    const int i = bid - 512;
    const float inv63 = 1.0f / 63.0f;
    for (int b = tid; b < BATCH; b += 256) {
      float xv = x[(size_t)b * D_IN + i];
      float xc = fminf(fmaxf(xv, 0.f), 1.f);
      int k0 = (int)(xc * 63.0f);
      k0 = min(k0, KK - 2);
      float x0 = (float)k0 * inv63;
      if (xc < x0)                              { k0--; x0 -= inv63; }
      else if (k0 < KK - 2 && xc >= x0 + inv63) { k0++; x0 += inv63; }
      float t  = (xc - x0) * 63.0f;
      float t2 = t * t;
      float t3 = t2 * t;
      float wy0 = 2.f * t3 - 3.f * t2 + 1.f;   // h00
      float wy1 = 3.f * t2 - 2.f * t3;         // h01
      float wd0 = t3 - 2.f * t2 + t;           // h10 (h folded into table)
      float wd1 = t3 - t2;                     // h11
      uint2 w;
      w.x = packh2(wy0, wd0);                  // pairs with {C[k0],   Dh[k0]}
      w.y = packh2(wy1, wd1);                  // pairs with {C[k0+1], Dh[k0+1]}
      W8[(size_t)i * BATCH + b] = w;
      K0[(size_t)i * BATCH + b] = (unsigned char)k0;
    }
  }
}

// ---------- kernel 2: LDS-staged main -------------------------------------------
// Block: 1024 thr = 16 waves. Covers (o-quarter 128 o) x (BT=256 b) x (CI i's).
// Per i: one 32 KB slab staged (reg-staged, double-buffered, 1 barrier/iter),
// consumed by 32 b-groups -> staging writes per unit work HALVED vs BT=128.
// Thread (g=tid&31, s=tid>>5): og 4g..4g+3, b's bbase..bbase+7.
// chunk = bid & (NCH-1) -> XCD-pinned 4 MiB PK slice (L2-resident).

template<int LG>
__global__ __launch_bounds__(1024, 8)
void kan_main(const uint2* __restrict__ W8, const unsigned char* __restrict__ K0,
              const uint4* __restrict__ pkq, __half* __restrict__ P) {
  __shared__ uint4 sb[2][2048];              // 2 x 32 KB

  const int CIk   = D_IN >> LG;
  const int bid   = blockIdx.x;
  const int chunk = bid & ((1 << LG) - 1);   // low bits -> XCD lane
  const int rest  = bid >> LG;
  const int oq    = rest & 3;
  const int btile = rest >> 2;               // 0..15
  const int tid   = threadIdx.x;
  const int g     = tid & 31;                // og-group of 4
  const int s     = tid >> 5;                // 0..31 -> 8 b's each
  const int bbase = btile * BT + s * 8;
  const int i0    = chunk * CIk;

  float acc[8][4];
#pragma unroll
  for (int j = 0; j < 8; ++j)
#pragma unroll
    for (int m = 0; m < 4; ++m) acc[j][m] = 0.f;

  // ---- prologue: k8(i0), stage slab(i0) into buf 0 ----
  uint64_t k8 = *(const uint64_t*)(K0 + (size_t)i0 * BATCH + bbase);
  {
    const uint4* src = pkq + ((size_t)((i0 << 2) + oq) << 11);
    uint4 r0 = src[tid], r1 = src[tid + 1024];
    sb[0][tid] = r0; sb[0][tid + 1024] = r1;
  }
  __syncthreads();

  for (int ic = 0; ic < CIk; ++ic) {
    const int cur = ic & 1;
    const int i   = i0 + ic;
    const bool more = (ic + 1 < CIk);

    // ---- issue next-i slab loads + k8 prefetch (overlap with consume) ----
    uint4 r0, r1;
    uint64_t k8n = 0;
    if (more) {
      const uint4* src = pkq + ((size_t)(((i + 1) << 2) + oq) << 11);
      r0 = src[tid]; r1 = src[tid + 1024];
      k8n = *(const uint64_t*)(K0 + (size_t)(i + 1) * BATCH + bbase);
    }

    // ---- W for current i (latency hides under the 16 ds_reads) ----
    uint4 wreg[4];
    const uint4* wp = (const uint4*)(W8 + (size_t)i * BATCH + bbase);
#pragma unroll
    for (int n = 0; n < 4; ++n) wreg[n] = wp[n];

    // ---- consume current slab from LDS ----
    const uint4* bufc = sb[cur];
#pragma unroll
    for (int j = 0; j < 8; ++j) {
      const uint32_t k0 = (uint32_t)(k8 >> (8 * j)) & 0xFFu;
      const uint4* p = bufc + k0 * 32 + g;
      uint4 q0 = p[0];                        // {C,Dh} og 4g..4g+3, row k0
      uint4 q1 = p[32];                       // row k0+1
      uint4 t  = wreg[j >> 1];
      uint32_t w0 = (j & 1) ? t.z : t.x;      // {wy0,wd0}
      uint32_t w1 = (j & 1) ? t.w : t.y;      // {wy1,wd1}
      acc[j][0] = dot2(q0.x, w0, acc[j][0]); acc[j][0] = dot2(q1.x, w1, acc[j][0]);
      acc[j][1] = dot2(q0.y, w0, acc[j][1]); acc[j][1] = dot2(q1.y, w1, acc[j][1]);
      acc[j][2] = dot2(q0.z, w0, acc[j][2]); acc[j][2] = dot2(q1.z, w1, acc[j][2]);
      acc[j][3] = dot2(q0.w, w0, acc[j][3]); acc[j][3] = dot2(q1.w, w1, acc[j][3]);
    }

    // ---- write next slab into other buffer ----
    if (more) {
      uint4* bufn = sb[cur ^ 1];
      bufn[tid] = r0; bufn[tid + 1024] = r1;
      k8 = k8n;
    }
    __syncthreads();
  }

  // ---- fp16 partials P[chunk][b][o] ----
  const size_t pb = ((size_t)chunk * BATCH + bbase) * D_OUT + oq * 128 + g * 4;
#pragma unroll
  for (int j = 0; j < 8; ++j) {
    uint2 h;
    h.x = packh2(acc[j][0], acc[j][1]);
    h.y = packh2(acc[j][2], acc[j][3]);
    *(uint2*)((char*)P + (pb + (size_t)j * D_OUT) * 2) = h;
  }
}

// ---------- kernel 3: reduce fp16 partials + bias --------------------------------

__global__ __launch_bounds__(256)
void kan_reduce(const __half* __restrict__ P, const float* __restrict__ bias,
                float* __restrict__ out, int nchunk) {
  const size_t t = (size_t)blockIdx.x * 256 + threadIdx.x;  // 4-o unit
  const int o4 = (int)(t & 127);
  float4 sum = ((const float4*)bias)[o4];
  for (int c = 0; c < nchunk; ++c) {
    uint2 h = *(const uint2*)((const char*)P +
              ((size_t)c * BATCH * D_OUT + t * 4) * 2);
    __half2 h01 = __builtin_bit_cast(__half2, h.x);
    __half2 h23 = __builtin_bit_cast(__half2, h.y);
    sum.x += __half2float(h01.x); sum.y += __half2float(h01.y);
    sum.z += __half2float(h23.x); sum.w += __half2float(h23.y);
  }
  ((float4*)out)[t] = sum;
}

// ---------- launch ---------------------------------------------------------------

extern "C" void kernel_launch(void* const* d_in, const int* in_sizes, int n_in,
                              void* d_out, int out_size, void* d_ws, size_t ws_size,
                              hipStream_t stream) {
  const float* x      = (const float*)d_in[0];
  const float* coeffs = (const float*)d_in[1];
  const float* bias   = (const float*)d_in[2];
  const float* knots  = (const float*)d_in[3];
  float* out = (float*)d_out;

  const size_t pk_bytes = (size_t)D_IN * KK * D_OUT * 4;     // 32 MiB
  const size_t w_bytes  = (size_t)D_IN * BATCH * 8;          //  8 MiB
  const size_t k_bytes  = (size_t)D_IN * BATCH;              //  1 MiB
  const size_t fixed    = pk_bytes + w_bytes + k_bytes;      // 41 MiB
  const size_t p_one    = (size_t)BATCH * D_OUT * 2;         //  4 MiB fp16 partial

  int lg = 3;                                                // prefer 8 chunks
  if (ws_size < fixed + (p_one << 3)) lg = 2;                // 73 -> 57 MiB
  if (ws_size < fixed + (p_one << lg)) return;               // loud failure
  const int nchunk = 1 << lg;

  char* ws = (char*)d_ws;
  uint32_t*      pk2p = (uint32_t*)ws;
  uint2*         W8   = (uint2*)(ws + pk_bytes);
  unsigned char* K0   = (unsigned char*)(ws + pk_bytes + w_bytes);
  __half*        P    = (__half*)(ws + fixed);

  kan_prep<<<dim3(768), 256, 0, stream>>>(coeffs, knots, x, pk2p, W8, K0);
  if (lg == 3)
    kan_main<3><<<dim3(16 * 4 * 8), 1024, 0, stream>>>(W8, K0, (const uint4*)pk2p, P);
  else
    kan_main<2><<<dim3(16 * 4 * 4), 1024, 0, stream>>>(W8, K0, (const uint4*)pk2p, P);
  kan_reduce<<<dim3(BATCH * D_OUT / 4 / 256), 256, 0, stream>>>(P, bias, out, nchunk);
}

// Round 9
// 116.318 us; speedup vs baseline: 2.7493x; 1.0887x over previous
//
#include <hip/hip_runtime.h>
#include <hip/hip_fp16.h>
#include <cstdint>

#define D_IN   256
#define D_OUT  512
#define KK     64
#define BATCH  4096
#define EPSF   1e-12f
#define BT     256               // batch rows per block (1024 threads)

// ---------- helpers ----------------------------------------------------------

using half2v = _Float16 __attribute__((ext_vector_type(2)));

__device__ __forceinline__ float dot2(uint32_t a, uint32_t b, float c) {
#if defined(__has_builtin) && __has_builtin(__builtin_amdgcn_fdot2)
  return __builtin_amdgcn_fdot2(__builtin_bit_cast(half2v, a),
                                __builtin_bit_cast(half2v, b), c, false);
#else
  __half2 ah = __builtin_bit_cast(__half2, a);
  __half2 bh = __builtin_bit_cast(__half2, b);
  return c + __half2float(ah.x) * __half2float(bh.x)
           + __half2float(ah.y) * __half2float(bh.y);
#endif
}

__device__ __forceinline__ uint32_t packh2(float a, float b) {
  __half2 h = __floats2half2_rn(a, b);
  return __builtin_bit_cast(uint32_t, h);
}

// async global->LDS DMA, 16B per lane; LDS dest = wave-uniform base + lane*16
__device__ __forceinline__ void stage16(const void* g, void* l) {
  __builtin_amdgcn_global_load_lds(
      (const __attribute__((address_space(1))) unsigned int*)g,
      (__attribute__((address_space(3))) unsigned int*)l,
      16, 0, 0);
}

// ---------- kernel 1: fused prep ------------------------------------------------
// Blocks [0,512): PCHIP slopes -> fp16 pair table, staging-permuted:
//   pk2p[((i*4+oq)*64 + k)*128 + og] = {C[o,i,k], d[o,i,k]*(h_k+EPS)}, o=oq*128+og
// Blocks [512,768): per-(b,i) Hermite weights (8B) + interval index (1B).

__global__ __launch_bounds__(256)
void kan_prep(const float* __restrict__ coeffs, const float* __restrict__ knots,
              const float* __restrict__ x,
              uint32_t* __restrict__ pk2p, uint2* __restrict__ W8,
              unsigned char* __restrict__ K0) {
  __shared__ float s_kn[KK];
  __shared__ float s_h[KK];
  const int bid = blockIdx.x;
  const int tid = threadIdx.x;

  if (bid < 512) {
    // ---------------- pack body ----------------
    if (tid < KK) s_kn[tid] = knots[tid];
    __syncthreads();
    if (tid < KK - 1) s_h[tid] = s_kn[tid + 1] - s_kn[tid];
    __syncthreads();

    const int i = bid >> 1;
    const int o = (bid & 1) * 256 + tid;
    const float* C = coeffs + ((size_t)o * D_IN + i) * KK;

    float c[KK];
#pragma unroll
    for (int k = 0; k < KK; k += 4) {
      float4 v = *(const float4*)(C + k);
      c[k] = v.x; c[k + 1] = v.y; c[k + 2] = v.z; c[k + 3] = v.w;
    }

    float d[KK];
    float h0 = s_h[0], h1 = s_h[1];
    float del0 = (c[1] - c[0]) / (h0 + EPSF);
    float del1 = (c[2] - c[1]) / (h1 + EPSF);
    {
      float di = ((2.f * h0 + h1) * del0 - h0 * del1) / (h0 + h1 + EPSF);
      di = (di * del0 <= 0.f) ? 0.f : di;
      di = (fabsf(di) > 3.f * fabsf(del0)) ? 3.f * del0 : di;
      d[0] = di;
    }
    float dp = del0, dn = del1;
#pragma unroll
    for (int k = 1; k <= KK - 2; ++k) {
      float hk = s_h[k], hkm = s_h[k - 1];
      float w1 = 2.f * hk + hkm;
      float w2 = hk + 2.f * hkm;
      float dint = (w1 + w2) / (w1 / (dp + EPSF) + w2 / (dn + EPSF) + EPSF);
      d[k] = (dp * dn > 0.f) ? dint : 0.f;
      if (k < KK - 2) {
        float nd = (c[k + 2] - c[k + 1]) / (s_h[k + 1] + EPSF);
        dp = dn; dn = nd;
      }
    }
    {
      float hN = s_h[KK - 2], hNm = s_h[KK - 3];
      float di = ((2.f * hN + hNm) * dn - hN * dp) / (hN + hNm + EPSF);
      di = (di * dn <= 0.f) ? 0.f : di;
      di = (fabsf(di) > 3.f * fabsf(dn)) ? 3.f * dn : di;
      d[KK - 1] = di;
    }

    const int oq = o >> 7, og = o & 127;
#pragma unroll
    for (int k = 0; k < KK; ++k) {
      float hk = ((k < KK - 1) ? s_h[k] : s_h[KK - 2]) + EPSF;
      pk2p[((size_t)(((i << 2) + oq) << 6) + k) * 128 + og] = packh2(c[k], d[k] * hk);
    }
  } else {
    // ---------------- weights body ----------------
    const int i = bid - 512;
    const float inv63 = 1.0f / 63.0f;
    for (int b = tid; b < BATCH; b += 256) {
      float xv = x[(size_t)b * D_IN + i];
      float xc = fminf(fmaxf(xv, 0.f), 1.f);
      int k0 = (int)(xc * 63.0f);
      k0 = min(k0, KK - 2);
      float x0 = (float)k0 * inv63;
      if (xc < x0)                              { k0--; x0 -= inv63; }
      else if (k0 < KK - 2 && xc >= x0 + inv63) { k0++; x0 += inv63; }
      float t  = (xc - x0) * 63.0f;
      float t2 = t * t;
      float t3 = t2 * t;
      float wy0 = 2.f * t3 - 3.f * t2 + 1.f;   // h00
      float wy1 = 3.f * t2 - 2.f * t3;         // h01
      float wd0 = t3 - 2.f * t2 + t;           // h10 (h folded into table)
      float wd1 = t3 - t2;                     // h11
      uint2 w;
      w.x = packh2(wy0, wd0);                  // pairs with {C[k0],   Dh[k0]}
      w.y = packh2(wy1, wd1);                  // pairs with {C[k0+1], Dh[k0+1]}
      W8[(size_t)i * BATCH + b] = w;
      K0[(size_t)i * BATCH + b] = (unsigned char)k0;
    }
  }
}

// ---------- kernel 2: LDS-staged main (DMA staging) ----------------------------
// Block: 1024 thr = 16 waves. Covers (o-quarter 128 o) x (BT=256 b) x (CI i's).
// Per i: 32 KB slab staged via global_load_lds DMA (double-buffered, 1
// barrier/iter) -> zero ds_write issue slots; wave stream = 16 ds_read_b128 +
// 32 dot2 per thread-i. chunk = bid&(NCH-1) -> XCD-pinned L2-resident PK slice.

template<int LG>
__global__ __launch_bounds__(1024, 8)
void kan_main(const uint2* __restrict__ W8, const unsigned char* __restrict__ K0,
              const uint4* __restrict__ pkq, __half* __restrict__ P) {
  __shared__ uint4 sb[2][2048];              // 2 x 32 KB

  const int CIk   = D_IN >> LG;
  const int bid   = blockIdx.x;
  const int chunk = bid & ((1 << LG) - 1);   // low bits -> XCD lane
  const int rest  = bid >> LG;
  const int oq    = rest & 3;
  const int btile = rest >> 2;               // 0..15
  const int tid   = threadIdx.x;
  const int g     = tid & 31;                // og-group of 4
  const int s     = tid >> 5;                // 0..31 -> 8 b's each
  const int wv    = tid >> 6;                // wave 0..15
  const int bbase = btile * BT + s * 8;
  const int i0    = chunk * CIk;

  float acc[8][4];
#pragma unroll
  for (int j = 0; j < 8; ++j)
#pragma unroll
    for (int m = 0; m < 4; ++m) acc[j][m] = 0.f;

  // ---- prologue: k8(i0), DMA slab(i0) into buf 0 ----
  uint64_t k8 = *(const uint64_t*)(K0 + (size_t)i0 * BATCH + bbase);
  {
    const uint4* src = pkq + ((size_t)((i0 << 2) + oq) << 11);
    stage16(src + tid,        &sb[0][wv * 64]);
    stage16(src + tid + 1024, &sb[0][1024 + wv * 64]);
  }
  __syncthreads();

  for (int ic = 0; ic < CIk; ++ic) {
    const int cur = ic & 1;
    const int i   = i0 + ic;
    const bool more = (ic + 1 < CIk);

    // ---- issue next-i DMA + k8 prefetch (lands during consume) ----
    uint64_t k8n = 0;
    if (more) {
      const uint4* src = pkq + ((size_t)(((i + 1) << 2) + oq) << 11);
      uint4* bufn = sb[cur ^ 1];
      stage16(src + tid,        bufn + wv * 64);
      stage16(src + tid + 1024, bufn + 1024 + wv * 64);
      k8n = *(const uint64_t*)(K0 + (size_t)(i + 1) * BATCH + bbase);
    }

    // ---- W for current i (latency hides under the 16 ds_reads) ----
    uint4 wreg[4];
    const uint4* wp = (const uint4*)(W8 + (size_t)i * BATCH + bbase);
#pragma unroll
    for (int n = 0; n < 4; ++n) wreg[n] = wp[n];

    // ---- consume current slab from LDS ----
    const uint4* bufc = sb[cur];
#pragma unroll
    for (int j = 0; j < 8; ++j) {
      const uint32_t k0 = (uint32_t)(k8 >> (8 * j)) & 0xFFu;
      const uint4* p = bufc + k0 * 32 + g;
      uint4 q0 = p[0];                        // {C,Dh} og 4g..4g+3, row k0
      uint4 q1 = p[32];                       // row k0+1
      uint4 t  = wreg[j >> 1];
      uint32_t w0 = (j & 1) ? t.z : t.x;      // {wy0,wd0}
      uint32_t w1 = (j & 1) ? t.w : t.y;      // {wy1,wd1}
      acc[j][0] = dot2(q0.x, w0, acc[j][0]); acc[j][0] = dot2(q1.x, w1, acc[j][0]);
      acc[j][1] = dot2(q0.y, w0, acc[j][1]); acc[j][1] = dot2(q1.y, w1, acc[j][1]);
      acc[j][2] = dot2(q0.z, w0, acc[j][2]); acc[j][2] = dot2(q1.z, w1, acc[j][2]);
      acc[j][3] = dot2(q0.w, w0, acc[j][3]); acc[j][3] = dot2(q1.w, w1, acc[j][3]);
    }

    k8 = k8n;
    __syncthreads();   // drains DMA (vmcnt) -> next buffer ready
  }

  // ---- fp16 partials P[chunk][b][o] ----
  const size_t pb = ((size_t)chunk * BATCH + bbase) * D_OUT + oq * 128 + g * 4;
#pragma unroll
  for (int j = 0; j < 8; ++j) {
    uint2 h;
    h.x = packh2(acc[j][0], acc[j][1]);
    h.y = packh2(acc[j][2], acc[j][3]);
    *(uint2*)((char*)P + (pb + (size_t)j * D_OUT) * 2) = h;
  }
}

// ---------- kernel 3: reduce fp16 partials + bias (uint4-vectorized) ------------

__global__ __launch_bounds__(256)
void kan_reduce(const uint4* __restrict__ P4, const float* __restrict__ bias,
                float4* __restrict__ out4, int nchunk) {
  const size_t t = (size_t)blockIdx.x * 256 + threadIdx.x;  // 8-o unit
  const int o8 = (int)(t & 63);                             // D_OUT/8 - 1
  float4 s0 = ((const float4*)bias)[o8 * 2];
  float4 s1 = ((const float4*)bias)[o8 * 2 + 1];
  const size_t stride = (size_t)BATCH * D_OUT / 8;
  for (int c = 0; c < nchunk; ++c) {
    uint4 h = P4[(size_t)c * stride + t];
    __half2 a = __builtin_bit_cast(__half2, h.x);
    __half2 b = __builtin_bit_cast(__half2, h.y);
    __half2 cc = __builtin_bit_cast(__half2, h.z);
    __half2 d = __builtin_bit_cast(__half2, h.w);
    s0.x += __half2float(a.x);  s0.y += __half2float(a.y);
    s0.z += __half2float(b.x);  s0.w += __half2float(b.y);
    s1.x += __half2float(cc.x); s1.y += __half2float(cc.y);
    s1.z += __half2float(d.x);  s1.w += __half2float(d.y);
  }
  out4[t * 2]     = s0;
  out4[t * 2 + 1] = s1;
}

// ---------- launch ---------------------------------------------------------------

extern "C" void kernel_launch(void* const* d_in, const int* in_sizes, int n_in,
                              void* d_out, int out_size, void* d_ws, size_t ws_size,
                              hipStream_t stream) {
  const float* x      = (const float*)d_in[0];
  const float* coeffs = (const float*)d_in[1];
  const float* bias   = (const float*)d_in[2];
  const float* knots  = (const float*)d_in[3];
  float* out = (float*)d_out;

  const size_t pk_bytes = (size_t)D_IN * KK * D_OUT * 4;     // 32 MiB
  const size_t w_bytes  = (size_t)D_IN * BATCH * 8;          //  8 MiB
  const size_t k_bytes  = (size_t)D_IN * BATCH;              //  1 MiB
  const size_t fixed    = pk_bytes + w_bytes + k_bytes;      // 41 MiB
  const size_t p_one    = (size_t)BATCH * D_OUT * 2;         //  4 MiB fp16 partial

  int lg = 3;                                                // prefer 8 chunks
  if (ws_size < fixed + (p_one << 3)) lg = 2;                // 73 -> 57 MiB
  if (ws_size < fixed + (p_one << lg)) return;               // loud failure
  const int nchunk = 1 << lg;

  char* ws = (char*)d_ws;
  uint32_t*      pk2p = (uint32_t*)ws;
  uint2*         W8   = (uint2*)(ws + pk_bytes);
  unsigned char* K0   = (unsigned char*)(ws + pk_bytes + w_bytes);
  __half*        P    = (__half*)(ws + fixed);

  kan_prep<<<dim3(768), 256, 0, stream>>>(coeffs, knots, x, pk2p, W8, K0);
  if (lg == 3)
    kan_main<3><<<dim3(16 * 4 * 8), 1024, 0, stream>>>(W8, K0, (const uint4*)pk2p, P);
  else
    kan_main<2><<<dim3(16 * 4 * 4), 1024, 0, stream>>>(W8, K0, (const uint4*)pk2p, P);
  kan_reduce<<<dim3(BATCH * D_OUT / 8 / 256), 256, 0, stream>>>(
      (const uint4*)P, bias, (float4*)out, nchunk);
}

// Round 10
// 112.108 us; speedup vs baseline: 2.8525x; 1.0376x over previous
//
#include <hip/hip_runtime.h>
#include <hip/hip_fp16.h>
#include <cstdint>

#define D_IN   256
#define D_OUT  512
#define KK     64
#define BATCH  4096
#define EPSF   1e-12f
#define BT     256               // batch rows per block

// ---------- helpers ----------------------------------------------------------

using half2v = _Float16 __attribute__((ext_vector_type(2)));

__device__ __forceinline__ float dot2(uint32_t a, uint32_t b, float c) {
#if defined(__has_builtin) && __has_builtin(__builtin_amdgcn_fdot2)
  return __builtin_amdgcn_fdot2(__builtin_bit_cast(half2v, a),
                                __builtin_bit_cast(half2v, b), c, false);
#else
  __half2 ah = __builtin_bit_cast(__half2, a);
  __half2 bh = __builtin_bit_cast(__half2, b);
  return c + __half2float(ah.x) * __half2float(bh.x)
           + __half2float(ah.y) * __half2float(bh.y);
#endif
}

__device__ __forceinline__ uint32_t packh2(float a, float b) {
  __half2 h = __floats2half2_rn(a, b);
  return __builtin_bit_cast(uint32_t, h);
}

// async global->LDS DMA, 16B per lane; LDS dest = wave-uniform base + lane*16
__device__ __forceinline__ void stage16(const void* g, void* l) {
  __builtin_amdgcn_global_load_lds(
      (const __attribute__((address_space(1))) unsigned int*)g,
      (__attribute__((address_space(3))) unsigned int*)l,
      16, 0, 0);
}

// ---------- kernel 1: fused prep ------------------------------------------------
// Blocks [0,512): PCHIP slopes -> fp16 pair table, staging-permuted by o-EIGHTH:
//   pk2p[((i*8+oe)*64 + k)*64 + og] = {C[o,i,k], d[o,i,k]*(h_k+EPS)}, o=oe*64+og
//   -> slab (i,oe) = 16 KB contiguous (row = 256 B).
// Blocks [512,768): per-(b,i) Hermite weights (8B) + interval index (1B).

__global__ __launch_bounds__(256)
void kan_prep(const float* __restrict__ coeffs, const float* __restrict__ knots,
              const float* __restrict__ x,
              uint32_t* __restrict__ pk2p, uint2* __restrict__ W8,
              unsigned char* __restrict__ K0) {
  __shared__ float s_kn[KK];
  __shared__ float s_h[KK];
  const int bid = blockIdx.x;
  const int tid = threadIdx.x;

  if (bid < 512) {
    // ---------------- pack body ----------------
    if (tid < KK) s_kn[tid] = knots[tid];
    __syncthreads();
    if (tid < KK - 1) s_h[tid] = s_kn[tid + 1] - s_kn[tid];
    __syncthreads();

    const int i = bid >> 1;
    const int o = (bid & 1) * 256 + tid;
    const float* C = coeffs + ((size_t)o * D_IN + i) * KK;

    float c[KK];
#pragma unroll
    for (int k = 0; k < KK; k += 4) {
      float4 v = *(const float4*)(C + k);
      c[k] = v.x; c[k + 1] = v.y; c[k + 2] = v.z; c[k + 3] = v.w;
    }

    float d[KK];
    float h0 = s_h[0], h1 = s_h[1];
    float del0 = (c[1] - c[0]) / (h0 + EPSF);
    float del1 = (c[2] - c[1]) / (h1 + EPSF);
    {
      float di = ((2.f * h0 + h1) * del0 - h0 * del1) / (h0 + h1 + EPSF);
      di = (di * del0 <= 0.f) ? 0.f : di;
      di = (fabsf(di) > 3.f * fabsf(del0)) ? 3.f * del0 : di;
      d[0] = di;
    }
    float dp = del0, dn = del1;
#pragma unroll
    for (int k = 1; k <= KK - 2; ++k) {
      float hk = s_h[k], hkm = s_h[k - 1];
      float w1 = 2.f * hk + hkm;
      float w2 = hk + 2.f * hkm;
      float dint = (w1 + w2) / (w1 / (dp + EPSF) + w2 / (dn + EPSF) + EPSF);
      d[k] = (dp * dn > 0.f) ? dint : 0.f;
      if (k < KK - 2) {
        float nd = (c[k + 2] - c[k + 1]) / (s_h[k + 1] + EPSF);
        dp = dn; dn = nd;
      }
    }
    {
      float hN = s_h[KK - 2], hNm = s_h[KK - 3];
      float di = ((2.f * hN + hNm) * dn - hN * dp) / (hN + hNm + EPSF);
      di = (di * dn <= 0.f) ? 0.f : di;
      di = (fabsf(di) > 3.f * fabsf(dn)) ? 3.f * dn : di;
      d[KK - 1] = di;
    }

    const int oe = o >> 6, og = o & 63;
#pragma unroll
    for (int k = 0; k < KK; ++k) {
      float hk = ((k < KK - 1) ? s_h[k] : s_h[KK - 2]) + EPSF;
      pk2p[((size_t)(((i << 3) + oe) << 6) + k) * 64 + og] = packh2(c[k], d[k] * hk);
    }
  } else {
    // ---------------- weights body ----------------
    const int i = bid - 512;
    const float inv63 = 1.0f / 63.0f;
    for (int b = tid; b < BATCH; b += 256) {
      float xv = x[(size_t)b * D_IN + i];
      float xc = fminf(fmaxf(xv, 0.f), 1.f);
      int k0 = (int)(xc * 63.0f);
      k0 = min(k0, KK - 2);
      float x0 = (float)k0 * inv63;
      if (xc < x0)                              { k0--; x0 -= inv63; }
      else if (k0 < KK - 2 && xc >= x0 + inv63) { k0++; x0 += inv63; }
      float t  = (xc - x0) * 63.0f;
      float t2 = t * t;
      float t3 = t2 * t;
      float wy0 = 2.f * t3 - 3.f * t2 + 1.f;   // h00
      float wy1 = 3.f * t2 - 2.f * t3;         // h01
      float wd0 = t3 - 2.f * t2 + t;           // h10 (h folded into table)
      float wd1 = t3 - t2;                     // h11
      uint2 w;
      w.x = packh2(wy0, wd0);                  // pairs with {C[k0],   Dh[k0]}
      w.y = packh2(wy1, wd1);                  // pairs with {C[k0+1], Dh[k0+1]}
      W8[(size_t)i * BATCH + b] = w;
      K0[(size_t)i * BATCH + b] = (unsigned char)k0;
    }
  }
}

// ---------- kernel 2: LDS-staged main (DMA staging, 8-wave blocks) --------------
// Block: 512 thr = 8 waves. Covers (o-eighth 64 o) x (BT=256 b) x (CI i's).
// 4 blocks/CU (32 KB LDS each): narrow barriers, 3 other blocks hide each drain.
// Per i: 16 KB slab via global_load_lds DMA (double-buffered, 1 barrier/iter).
// Thread (g=tid&15, s=tid>>4): og 4g..4g+3, b's bbase..bbase+7.
// chunk = bid&7 -> XCD-pinned 4 MiB PK slice (L2-resident).

template<int LG>
__global__ __launch_bounds__(512, 8)
void kan_main(const uint2* __restrict__ W8, const unsigned char* __restrict__ K0,
              const uint4* __restrict__ pkq, __half* __restrict__ P) {
  __shared__ uint4 sb[2][1024];              // 2 x 16 KB

  const int CIk   = D_IN >> LG;
  const int bid   = blockIdx.x;
  const int chunk = bid & ((1 << LG) - 1);   // low bits -> XCD lane
  const int rest  = bid >> LG;
  const int oe    = rest & 7;
  const int btile = rest >> 3;               // 0..15
  const int tid   = threadIdx.x;
  const int g     = tid & 15;                // og-group of 4
  const int s     = tid >> 4;                // 0..31 -> 8 b's each
  const int wv    = tid >> 6;                // wave 0..7
  const int bbase = btile * BT + s * 8;
  const int i0    = chunk * CIk;

  float acc[8][4];
#pragma unroll
  for (int j = 0; j < 8; ++j)
#pragma unroll
    for (int m = 0; m < 4; ++m) acc[j][m] = 0.f;

  // ---- prologue: k8(i0), DMA slab(i0) into buf 0 ----
  uint64_t k8 = *(const uint64_t*)(K0 + (size_t)i0 * BATCH + bbase);
  {
    const uint4* src = pkq + ((size_t)((i0 << 3) + oe) << 10);
    stage16(src + tid,       &sb[0][wv * 64]);
    stage16(src + tid + 512, &sb[0][512 + wv * 64]);
  }
  __syncthreads();

  for (int ic = 0; ic < CIk; ++ic) {
    const int cur = ic & 1;
    const int i   = i0 + ic;
    const bool more = (ic + 1 < CIk);

    // ---- issue next-i DMA + k8 prefetch (lands during consume) ----
    uint64_t k8n = 0;
    if (more) {
      const uint4* src = pkq + ((size_t)(((i + 1) << 3) + oe) << 10);
      uint4* bufn = sb[cur ^ 1];
      stage16(src + tid,       bufn + wv * 64);
      stage16(src + tid + 512, bufn + 512 + wv * 64);
      k8n = *(const uint64_t*)(K0 + (size_t)(i + 1) * BATCH + bbase);
    }

    // ---- W for current i (latency hides under the 16 ds_reads) ----
    uint4 wreg[4];
    const uint4* wp = (const uint4*)(W8 + (size_t)i * BATCH + bbase);
#pragma unroll
    for (int n = 0; n < 4; ++n) wreg[n] = wp[n];

    // ---- consume current slab from LDS ----
    const uint4* bufc = sb[cur];
#pragma unroll
    for (int j = 0; j < 8; ++j) {
      const uint32_t k0 = (uint32_t)(k8 >> (8 * j)) & 0xFFu;
      const uint4* p = bufc + k0 * 16 + g;    // row = 16 uint4 (256 B)
      uint4 q0 = p[0];                        // {C,Dh} og 4g..4g+3, row k0
      uint4 q1 = p[16];                       // row k0+1
      uint4 t  = wreg[j >> 1];
      uint32_t w0 = (j & 1) ? t.z : t.x;      // {wy0,wd0}
      uint32_t w1 = (j & 1) ? t.w : t.y;      // {wy1,wd1}
      acc[j][0] = dot2(q0.x, w0, acc[j][0]); acc[j][0] = dot2(q1.x, w1, acc[j][0]);
      acc[j][1] = dot2(q0.y, w0, acc[j][1]); acc[j][1] = dot2(q1.y, w1, acc[j][1]);
      acc[j][2] = dot2(q0.z, w0, acc[j][2]); acc[j][2] = dot2(q1.z, w1, acc[j][2]);
      acc[j][3] = dot2(q0.w, w0, acc[j][3]); acc[j][3] = dot2(q1.w, w1, acc[j][3]);
    }

    k8 = k8n;
    __syncthreads();   // drains DMA (vmcnt) -> next buffer ready
  }

  // ---- fp16 partials P[chunk][b][o] ----
  const size_t pb = ((size_t)chunk * BATCH + bbase) * D_OUT + oe * 64 + g * 4;
#pragma unroll
  for (int j = 0; j < 8; ++j) {
    uint2 h;
    h.x = packh2(acc[j][0], acc[j][1]);
    h.y = packh2(acc[j][2], acc[j][3]);
    *(uint2*)((char*)P + (pb + (size_t)j * D_OUT) * 2) = h;
  }
}

// ---------- kernel 3: reduce fp16 partials + bias (uint4-vectorized) ------------

__global__ __launch_bounds__(256)
void kan_reduce(const uint4* __restrict__ P4, const float* __restrict__ bias,
                float4* __restrict__ out4, int nchunk) {
  const size_t t = (size_t)blockIdx.x * 256 + threadIdx.x;  // 8-o unit
  const int o8 = (int)(t & 63);                             // D_OUT/8 - 1
  float4 s0 = ((const float4*)bias)[o8 * 2];
  float4 s1 = ((const float4*)bias)[o8 * 2 + 1];
  const size_t stride = (size_t)BATCH * D_OUT / 8;
  for (int c = 0; c < nchunk; ++c) {
    uint4 h = P4[(size_t)c * stride + t];
    __half2 a = __builtin_bit_cast(__half2, h.x);
    __half2 b = __builtin_bit_cast(__half2, h.y);
    __half2 cc = __builtin_bit_cast(__half2, h.z);
    __half2 d = __builtin_bit_cast(__half2, h.w);
    s0.x += __half2float(a.x);  s0.y += __half2float(a.y);
    s0.z += __half2float(b.x);  s0.w += __half2float(b.y);
    s1.x += __half2float(cc.x); s1.y += __half2float(cc.y);
    s1.z += __half2float(d.x);  s1.w += __half2float(d.y);
  }
  out4[t * 2]     = s0;
  out4[t * 2 + 1] = s1;
}

// ---------- launch ---------------------------------------------------------------

extern "C" void kernel_launch(void* const* d_in, const int* in_sizes, int n_in,
                              void* d_out, int out_size, void* d_ws, size_t ws_size,
                              hipStream_t stream) {
  const float* x      = (const float*)d_in[0];
  const float* coeffs = (const float*)d_in[1];
  const float* bias   = (const float*)d_in[2];
  const float* knots  = (const float*)d_in[3];
  float* out = (float*)d_out;

  const size_t pk_bytes = (size_t)D_IN * KK * D_OUT * 4;     // 32 MiB
  const size_t w_bytes  = (size_t)D_IN * BATCH * 8;          //  8 MiB
  const size_t k_bytes  = (size_t)D_IN * BATCH;              //  1 MiB
  const size_t fixed    = pk_bytes + w_bytes + k_bytes;      // 41 MiB
  const size_t p_one    = (size_t)BATCH * D_OUT * 2;         //  4 MiB fp16 partial

  int lg = 3;                                                // prefer 8 chunks
  if (ws_size < fixed + (p_one << 3)) lg = 2;                // 73 -> 57 MiB
  if (ws_size < fixed + (p_one << lg)) return;               // loud failure
  const int nchunk = 1 << lg;

  char* ws = (char*)d_ws;
  uint32_t*      pk2p = (uint32_t*)ws;
  uint2*         W8   = (uint2*)(ws + pk_bytes);
  unsigned char* K0   = (unsigned char*)(ws + pk_bytes + w_bytes);
  __half*        P    = (__half*)(ws + fixed);

  kan_prep<<<dim3(768), 256, 0, stream>>>(coeffs, knots, x, pk2p, W8, K0);
  if (lg == 3)
    kan_main<3><<<dim3(16 * 8 * 8), 512, 0, stream>>>(W8, K0, (const uint4*)pk2p, P);
  else
    kan_main<2><<<dim3(16 * 8 * 4), 512, 0, stream>>>(W8, K0, (const uint4*)pk2p, P);
  kan_reduce<<<dim3(BATCH * D_OUT / 8 / 256), 256, 0, stream>>>(
      (const uint4*)P, bias, (float4*)out, nchunk);
}